// Round 9
// baseline (244.161 us; speedup 1.0000x reference)
//
#include <hip/hip_runtime.h>

typedef _Float16 half8 __attribute__((ext_vector_type(8)));
typedef float f32x4 __attribute__((ext_vector_type(4)));

#define H    4096
#define NE   160
#define BM   64
#define TPB  512
#define NIT  64            // iterations of 2 k-steps (K = 128 k-steps of 32)

// d_out layout (all float32): [0,98304) topk_idx, [98304,196608) topk_weight, [196608] aux_loss

// ---- prep: w[160][4096] fp32 -> k-step-major fragment pairs (w*64 = hi + lo/2048) ----
// half8 index for (ks, h, t10, lane): (ks*20 + h*10 + t10)*64 + lane
// holds expert e = t10*16 + (lane&15), k = ks*32 + (lane>>4)*8 .. +8
__global__ __launch_bounds__(256) void prep_kernel(
    const float* __restrict__ w, _Float16* __restrict__ Wf)
{
    int F    = blockIdx.x * 256 + threadIdx.x;   // 0..81919
    int lane = F & 63;
    int t10  = (F >> 6) % 10;
    int ks   = F / 640;
    int e    = t10 * 16 + (lane & 15);
    int k0   = ks * 32 + (lane >> 4) * 8;
    const float* p = w + (size_t)e * H + k0;
    float4 v0 = *(const float4*)p;
    float4 v1 = *(const float4*)(p + 4);
    float vv[8] = {v0.x, v0.y, v0.z, v0.w, v1.x, v1.y, v1.z, v1.w};
    half8 h0, h1;
#pragma unroll
    for (int j = 0; j < 8; ++j) {
        float s = vv[j] * 64.f;
        _Float16 a = (_Float16)s;
        h0[j] = a;
        h1[j] = (_Float16)((s - (float)a) * 2048.f);
    }
    half8* out = (half8*)Wf;
    out[(ks * 20 + t10) * 64 + lane]      = h0;   // hi
    out[(ks * 20 + 10 + t10) * 64 + lane] = h1;   // lo
}

#define GLOAD_LDS(SRC, DST)                                                    \
    __builtin_amdgcn_global_load_lds(                                          \
        (const __attribute__((address_space(1))) unsigned int*)(SRC),          \
        (__attribute__((address_space(3))) unsigned int*)(DST), 16, 0, 0)

#define LOADX(U0, U1, KIDX)                                                    \
    do {                                                                       \
        U0 = *(const float4*)(xp + (size_t)(KIDX) * 32);                       \
        U1 = *(const float4*)(xp + (size_t)(KIDX) * 32 + 4);                   \
    } while (0)

#define CONVERT(U0, U1)                                                        \
    do {                                                                       \
        float v0=U0.x, v1=U0.y, v2=U0.z, v3=U0.w;                              \
        float v4=U1.x, v5=U1.y, v6=U1.z, v7=U1.w;                              \
        _Float16 h;                                                            \
        h=(_Float16)v0; a0[0]=h; a1[0]=(_Float16)((v0-(float)h)*2048.f);       \
        h=(_Float16)v1; a0[1]=h; a1[1]=(_Float16)((v1-(float)h)*2048.f);       \
        h=(_Float16)v2; a0[2]=h; a1[2]=(_Float16)((v2-(float)h)*2048.f);       \
        h=(_Float16)v3; a0[3]=h; a1[3]=(_Float16)((v3-(float)h)*2048.f);       \
        h=(_Float16)v4; a0[4]=h; a1[4]=(_Float16)((v4-(float)h)*2048.f);       \
        h=(_Float16)v5; a0[5]=h; a1[5]=(_Float16)((v5-(float)h)*2048.f);       \
        h=(_Float16)v6; a0[6]=h; a1[6]=(_Float16)((v6-(float)h)*2048.f);       \
        h=(_Float16)v7; a0[7]=h; a1[7]=(_Float16)((v7-(float)h)*2048.f);       \
    } while (0)

// one k-step: read 10 fragments from stage buf at half8-offset CUR, convert x, 15 MFMA
#define KSTEP(CUR, LKS, U0, U1)                                                \
    do {                                                                       \
        const half8* _B = (const half8*)s_stage + (CUR) + (LKS) * 1280         \
                          + nh * 5 * 64 + lane;                                \
        half8 bb0[5], bb1[5];                                                  \
        _Pragma("unroll")                                                      \
        for (int _t = 0; _t < 5; ++_t) {                                       \
            bb0[_t] = _B[_t * 64];                                             \
            bb1[_t] = _B[640 + _t * 64];                                       \
        }                                                                      \
        CONVERT(U0, U1);                                                       \
        _Pragma("unroll")                                                      \
        for (int _t = 0; _t < 5; ++_t) {                                       \
            accH[_t] = __builtin_amdgcn_mfma_f32_16x16x32_f16(a0, bb0[_t], accH[_t], 0, 0, 0); \
            accL[_t] = __builtin_amdgcn_mfma_f32_16x16x32_f16(a1, bb0[_t], accL[_t], 0, 0, 0); \
            accL[_t] = __builtin_amdgcn_mfma_f32_16x16x32_f16(a0, bb1[_t], accL[_t], 0, 0, 0); \
        }                                                                      \
    } while (0)

__global__ __launch_bounds__(TPB) void gate_kernel(
    const float* __restrict__ x, const _Float16* __restrict__ Wf,
    float* __restrict__ outIdx, float* __restrict__ outW,
    float* __restrict__ gcnt, float* __restrict__ gssum)
{
    // 3 stage buffers x (2 k-steps x 1280 half8 x 16B) = 122880 B; s_log aliases it
    __shared__ __align__(16) _Float16 s_stage[3 * 2560 * 8];
    __shared__ float s_mx[BM], s_inv[BM];
    __shared__ int   s_cnt[NE];
    float* s_log = (float*)s_stage;   // [64][161] after the K-loop

    const int tid  = threadIdx.x;
    const int lane = tid & 63;
    const int wv   = tid >> 6;        // 8 waves: mh(4) x nh(2)
    const int mh   = wv >> 1;
    const int nh   = wv & 1;
    const int row0 = blockIdx.x * BM;
    const int rowl = mh * 16 + (lane & 15);
    const int kq   = (lane >> 4) * 8;

    if (tid < NE) s_cnt[tid] = 0;
    __syncthreads();   // s_cnt init done before any wave reaches epilogue

    f32x4 accH[5], accL[5];
#pragma unroll
    for (int t = 0; t < 5; ++t) { accH[t] = (f32x4){0,0,0,0}; accL[t] = (f32x4){0,0,0,0}; }

    const float* xp = x + (size_t)(row0 + rowl) * H + kq;

    half8 a0, a1;
    // 3 generations of x registers (batch it / it+1 / it+2)
    float4 aU0, aU1, aV0, aV1, bU0, bU1, bV0, bV1, cU0, cU1, cV0, cV1;

    // ---- prologue: issue batch 0 (stage buf0 + x gen A) and batch 1 (buf1 + x gen B)
    {
        const _Float16* src = Wf + (size_t)tid * 8;
        _Float16*       dst = s_stage + (size_t)tid * 8;
#pragma unroll
        for (int i = 0; i < 5; ++i) GLOAD_LDS(src + i * 4096, dst + i * 4096);
    }
    LOADX(aU0, aU1, 0);
    LOADX(aV0, aV1, 1);
    {
        const _Float16* src = Wf + ((size_t)2560 + tid) * 8;
        _Float16*       dst = s_stage + ((size_t)2560 + tid) * 8;
#pragma unroll
        for (int i = 0; i < 5; ++i) GLOAD_LDS(src + i * 4096, dst + i * 4096);
    }
    LOADX(bU0, bU1, 2);
    LOADX(bV0, bV1, 3);

    int c0 = 0, c1 = 2560, c2 = 5120;   // half8 offsets of buf[it%3], [it+1], [it+2]

    for (int it = 0; it < NIT; ++it) {
        // retire batch it (9 VMEM): leaves batch it+1 (9) outstanding
        asm volatile("s_waitcnt vmcnt(9)" ::: "memory");
        __builtin_amdgcn_s_barrier();   // batch-it LDS writes visible; buf c2 free

        // issue batch it+2 (5 stage gloads into buf c2 + 4 x loads), wraps harmlessly
        {
            const _Float16* src = Wf + ((size_t)(it + 2) * 2560 + tid) * 8;
            _Float16*       dst = s_stage + ((size_t)c2 + tid) * 8;
#pragma unroll
            for (int i = 0; i < 5; ++i) GLOAD_LDS(src + i * 4096, dst + i * 4096);
        }
        {
            const int kb = (2 * (it + 2)) & (2 * NIT - 1);
            LOADX(cU0, cU1, kb);
            LOADX(cV0, cV1, kb + 1);
        }
        __builtin_amdgcn_sched_barrier(0);   // pin the 9 VMEM issues above the compute

        // compute the 2 k-steps of batch it from buf c0
        KSTEP(c0, 0, aU0, aU1);
        KSTEP(c0, 1, aV0, aV1);

        // rotate x generations and buffers
        aU0 = bU0; aU1 = bU1; aV0 = bV0; aV1 = bV1;
        bU0 = cU0; bU1 = cU1; bV0 = cV0; bV1 = cV1;
        int t0 = c0; c0 = c1; c1 = c2; c2 = t0;
    }

    // drain wrapped batches before s_log aliases the stage memory
    asm volatile("s_waitcnt vmcnt(0)" ::: "memory");
    __syncthreads();

    // ---- write logits; C layout col=lane&15, row=(lane>>4)*4+reg ----
    const int crow  = mh * 16 + (lane >> 4) * 4;
    const int ccol0 = nh * 80 + (lane & 15);
#pragma unroll
    for (int t = 0; t < 5; ++t)
#pragma unroll
        for (int r = 0; r < 4; ++r)
            s_log[(crow + r) * 161 + ccol0 + t * 16] =
                (accH[t][r] + accL[t][r] * (1.0f / 2048.f)) * (1.0f / 64.f);
    __syncthreads();

    // ---- per-token softmax + group top-3 + expert top-6 (threads 0..63) ----
    if (tid < BM) {
        const float* L = &s_log[tid * 161];
        float gmax[8];
        float mx = -3.4e38f;
#pragma unroll
        for (int g = 0; g < 8; ++g) {
            float m = L[g * 20];
            for (int j = 1; j < 20; ++j) m = fmaxf(m, L[g * 20 + j]);
            gmax[g] = m;
            mx = fmaxf(mx, m);
        }
        float sum = 0.f;
        for (int e = 0; e < NE; ++e) sum += __expf(L[e] - mx);
        float inv = 1.0f / sum;
        s_mx[tid]  = mx;
        s_inv[tid] = inv;

        // top-3 groups, lax.top_k tie semantics (value desc, index asc)
        unsigned sel = 0;
        float pv = 3.4e38f; int pi = -1;
        for (int it = 0; it < 3; ++it) {
            float bv = -3.4e38f; int bi = 0;
            for (int g = 0; g < 8; ++g) {
                float v = gmax[g];
                bool below = (v < pv) || (v == pv && g > pi);
                if (below && v > bv) { bv = v; bi = g; }
            }
            sel |= 1u << bi;
            pv = bv; pi = bi;
        }

        // top-6 experts within selected groups
        const int tok = row0 + tid;
        float pv2 = 3.4e38f; int pi2 = -1;
        for (int it = 0; it < 6; ++it) {
            float bv = -3.4e38f; int bi = 0;
            for (int g = 0; g < 8; ++g) {
                if (!((sel >> g) & 1u)) continue;
                for (int j = 0; j < 20; ++j) {
                    int e = g * 20 + j;
                    float v = L[e];
                    bool below = (v < pv2) || (v == pv2 && e > pi2);
                    if (below && v > bv) { bv = v; bi = e; }
                }
            }
            pv2 = bv; pi2 = bi;
            outIdx[(size_t)tok * 6 + it] = (float)bi;
            outW[(size_t)tok * 6 + it]   = __expf(bv - mx) * inv * 16.0f;
            atomicAdd(&s_cnt[bi], 1);
        }
    }
    __syncthreads();

    // ---- per-block expert score-sum + counts -> global (batch, expert) bins ----
    if (tid < NE) {
        float ss = 0.f;
        for (int t2 = 0; t2 < BM; ++t2)
            ss += __expf(s_log[t2 * 161 + tid] - s_mx[t2]) * s_inv[t2];
        const int b = row0 >> 12;   // 4096 tokens per batch
        atomicAdd(&gssum[b * NE + tid], ss);
        atomicAdd(&gcnt[b * NE + tid], (float)s_cnt[tid]);
    }
}

__global__ __launch_bounds__(64) void aux_kernel(
    const float* __restrict__ gcnt, const float* __restrict__ gssum,
    float* __restrict__ out)
{
    const int lane = threadIdx.x;
    float part = 0.f;
    if (lane < 32) {
        const int b = lane >> 3, g = lane & 7;
        const float* cn = gcnt  + b * NE + g * 20;
        const float* sm = gssum + b * NE + g * 20;
        float s1 = 0.f, sc = 0.f, sms = 0.f;
        for (int j = 0; j < 20; ++j) {
            float ce = cn[j] * (1.0f / 153.6f);   // counts / (s*k/E)
            float ms = sm[j] * (1.0f / 4096.0f);  // mean over s
            s1  += ce * ms;
            sc  += cn[j];
            sms += ms;
        }
        float ceg = sc * (1.0f / 153.6f) * (1.0f / 20.0f);
        float msg = sms * (1.0f / 20.0f);
        float ce2 = sc * (1.0f / 1536.0f);        // counts_g / (M*s/G)
        part = s1 + ceg * msg + ce2 * msg;
    }
#pragma unroll
    for (int off = 32; off > 0; off >>= 1) part += __shfl_down(part, off);
    if (lane == 0) out[0] = part * (0.001f * 0.25f);  // ALPHA * mean over B=4
}

extern "C" void kernel_launch(void* const* d_in, const int* in_sizes, int n_in,
                              void* d_out, int out_size, void* d_ws, size_t ws_size,
                              hipStream_t stream)
{
    (void)in_sizes; (void)n_in; (void)out_size; (void)ws_size;
    const float* x = (const float*)d_in[0];
    const float* w = (const float*)d_in[1];
    float* out = (float*)d_out;

    _Float16* Wf  = (_Float16*)d_ws;                  // [128][2][10][64][8] halves
    float* gcnt  = (float*)(Wf + (size_t)NE * H * 2); // [4][160]
    float* gssum = gcnt + 4 * NE;                     // [4][160]

    hipMemsetAsync(gcnt, 0, 2 * 4 * NE * sizeof(float), stream);

    prep_kernel<<<(NE * H / 8) / 256, 256, 0, stream>>>(w, Wf);
    gate_kernel<<<16384 / BM, TPB, 0, stream>>>(
        x, Wf, out, out + 98304, gcnt, gssum);
    aux_kernel<<<1, 64, 0, stream>>>(gcnt, gssum, out + 196608);
}

// Round 10
// 226.537 us; speedup vs baseline: 1.0778x; 1.0778x over previous
//
#include <hip/hip_runtime.h>

typedef _Float16 half8 __attribute__((ext_vector_type(8)));
typedef float f32x4 __attribute__((ext_vector_type(4)));

#define H    4096
#define NE   160
#define BM   64
#define TPB  512
#define NIT  64            // iterations of 2 k-steps (K = 128 k-steps of 32)

// d_out layout (all float32): [0,98304) topk_idx, [98304,196608) topk_weight, [196608] aux_loss

// ---- prep: w[160][4096] fp32 -> k-step-major fragment pairs (w*64 = hi + lo/2048) ----
// half8 index for (ks, h, t10, lane): (ks*20 + h*10 + t10)*64 + lane
// holds expert e = t10*16 + (lane&15), k = ks*32 + (lane>>4)*8 .. +8
__global__ __launch_bounds__(256) void prep_kernel(
    const float* __restrict__ w, _Float16* __restrict__ Wf)
{
    int F    = blockIdx.x * 256 + threadIdx.x;   // 0..81919
    int lane = F & 63;
    int t10  = (F >> 6) % 10;
    int ks   = F / 640;
    int e    = t10 * 16 + (lane & 15);
    int k0   = ks * 32 + (lane >> 4) * 8;
    const float* p = w + (size_t)e * H + k0;
    float4 v0 = *(const float4*)p;
    float4 v1 = *(const float4*)(p + 4);
    float vv[8] = {v0.x, v0.y, v0.z, v0.w, v1.x, v1.y, v1.z, v1.w};
    half8 h0, h1;
#pragma unroll
    for (int j = 0; j < 8; ++j) {
        float s = vv[j] * 64.f;
        _Float16 a = (_Float16)s;
        h0[j] = a;
        h1[j] = (_Float16)((s - (float)a) * 2048.f);
    }
    half8* out = (half8*)Wf;
    out[(ks * 20 + t10) * 64 + lane]      = h0;   // hi
    out[(ks * 20 + 10 + t10) * 64 + lane] = h1;   // lo
}

#define GLOAD_LDS(SRC, DST)                                                    \
    __builtin_amdgcn_global_load_lds(                                          \
        (const __attribute__((address_space(1))) unsigned int*)(SRC),          \
        (__attribute__((address_space(3))) unsigned int*)(DST), 16, 0, 0)

// stage batch ITN into LDS buffer at half8-offset BUFOFF (5 DMA, 16B/lane)
#define STAGE(BUFOFF, ITN)                                                     \
    do {                                                                       \
        const int _its = ((ITN) < NIT) ? (ITN) : (NIT - 1);                    \
        const _Float16* _src = Wf + ((size_t)_its * 2560 + tid) * 8;           \
        _Float16*       _dst = s_stage + ((size_t)(BUFOFF) + tid) * 8;         \
        _Pragma("unroll")                                                      \
        for (int _i = 0; _i < 5; ++_i)                                         \
            GLOAD_LDS(_src + _i * 4096, _dst + _i * 4096);                     \
    } while (0)

// load x for batch ITN (2 k-steps = 4 float4)
#define XLOAD(U0, U1, V0, V1, ITN)                                             \
    do {                                                                       \
        const int _kb = (2 * (ITN)) & (2 * NIT - 1);                           \
        U0 = *(const float4*)(xp + (size_t)_kb * 32);                          \
        U1 = *(const float4*)(xp + (size_t)_kb * 32 + 4);                      \
        V0 = *(const float4*)(xp + (size_t)(_kb + 1) * 32);                    \
        V1 = *(const float4*)(xp + (size_t)(_kb + 1) * 32 + 4);                \
    } while (0)

#define CONVERT(U0, U1)                                                        \
    do {                                                                       \
        float v0=U0.x, v1=U0.y, v2=U0.z, v3=U0.w;                              \
        float v4=U1.x, v5=U1.y, v6=U1.z, v7=U1.w;                              \
        _Float16 h;                                                            \
        h=(_Float16)v0; a0[0]=h; a1[0]=(_Float16)((v0-(float)h)*2048.f);       \
        h=(_Float16)v1; a0[1]=h; a1[1]=(_Float16)((v1-(float)h)*2048.f);       \
        h=(_Float16)v2; a0[2]=h; a1[2]=(_Float16)((v2-(float)h)*2048.f);       \
        h=(_Float16)v3; a0[3]=h; a1[3]=(_Float16)((v3-(float)h)*2048.f);       \
        h=(_Float16)v4; a0[4]=h; a1[4]=(_Float16)((v4-(float)h)*2048.f);       \
        h=(_Float16)v5; a0[5]=h; a1[5]=(_Float16)((v5-(float)h)*2048.f);       \
        h=(_Float16)v6; a0[6]=h; a1[6]=(_Float16)((v6-(float)h)*2048.f);       \
        h=(_Float16)v7; a0[7]=h; a1[7]=(_Float16)((v7-(float)h)*2048.f);       \
    } while (0)

// one k-step: read 10 fragments from stage buf at half8-offset CUR, convert x, 15 MFMA
#define KSTEP(CUR, LKS, U0, U1)                                                \
    do {                                                                       \
        const half8* _B = (const half8*)s_stage + (CUR) + (LKS) * 1280         \
                          + nh * 5 * 64 + lane;                                \
        half8 bb0[5], bb1[5];                                                  \
        _Pragma("unroll")                                                      \
        for (int _t = 0; _t < 5; ++_t) {                                       \
            bb0[_t] = _B[_t * 64];                                             \
            bb1[_t] = _B[640 + _t * 64];                                       \
        }                                                                      \
        half8 a0, a1;                                                          \
        CONVERT(U0, U1);                                                       \
        _Pragma("unroll")                                                      \
        for (int _t = 0; _t < 5; ++_t) {                                       \
            accH[_t] = __builtin_amdgcn_mfma_f32_16x16x32_f16(a0, bb0[_t], accH[_t], 0, 0, 0); \
            accL[_t] = __builtin_amdgcn_mfma_f32_16x16x32_f16(a1, bb0[_t], accL[_t], 0, 0, 0); \
            accL[_t] = __builtin_amdgcn_mfma_f32_16x16x32_f16(a0, bb1[_t], accL[_t], 0, 0, 0); \
        }                                                                      \
    } while (0)

// one pipeline phase: retire batch IT, barrier, issue batch IT+2, compute batch IT
#define PHASE(IT, CBUF, FBUF, XU0, XU1, XV0, XV1, YU0, YU1, YV0, YV1)          \
    do {                                                                       \
        asm volatile("s_waitcnt vmcnt(9)" ::: "memory");                       \
        __builtin_amdgcn_s_barrier();                                          \
        STAGE(FBUF, (IT) + 2);                                                 \
        XLOAD(YU0, YU1, YV0, YV1, (IT) + 2);                                   \
        __builtin_amdgcn_sched_barrier(0);                                     \
        KSTEP(CBUF, 0, XU0, XU1);                                              \
        KSTEP(CBUF, 1, XV0, XV1);                                              \
    } while (0)

__global__ __launch_bounds__(TPB) void gate_kernel(
    const float* __restrict__ x, const _Float16* __restrict__ Wf,
    float* __restrict__ outIdx, float* __restrict__ outW,
    float* __restrict__ gcnt, float* __restrict__ gssum)
{
    // 3 stage buffers x (2 k-steps x 1280 half8 x 16B) = 122880 B; s_log aliases it
    __shared__ __align__(16) _Float16 s_stage[3 * 2560 * 8];
    __shared__ float s_mx[BM], s_inv[BM];
    __shared__ int   s_cnt[NE];
    float* s_log = (float*)s_stage;   // [64][161] after the K-loop

    const int tid  = threadIdx.x;
    const int lane = tid & 63;
    const int wv   = tid >> 6;        // 8 waves: mh(4) x nh(2)
    const int mh   = wv >> 1;
    const int nh   = wv & 1;
    const int row0 = blockIdx.x * BM;
    const int rowl = mh * 16 + (lane & 15);
    const int kq   = (lane >> 4) * 8;

    if (tid < NE) s_cnt[tid] = 0;
    __syncthreads();

    f32x4 accH[5], accL[5];
#pragma unroll
    for (int t = 0; t < 5; ++t) { accH[t] = (f32x4){0,0,0,0}; accL[t] = (f32x4){0,0,0,0}; }

    const float* xp = x + (size_t)(row0 + rowl) * H + kq;

    // three named x-register generations -- NO rotation movs anywhere
    float4 x0U0, x0U1, x0V0, x0V1;
    float4 x1U0, x1U1, x1V0, x1V1;
    float4 x2U0, x2U1, x2V0, x2V1;

    // prologue: issue batch 0 (buf0, X0) and batch 1 (buf1, X1) -> 18 outstanding
    STAGE(0, 0);
    XLOAD(x0U0, x0U1, x0V0, x0V1, 0);
    STAGE(2560, 1);
    XLOAD(x1U0, x1U1, x1V0, x1V1, 1);

    // static modulo-3 schedule: phase(it) computes buf[it%3]/X[it%3],
    // issues batch it+2 into buf[(it+2)%3]/X[(it+2)%3]
    for (int it = 0; it < NIT - 1; it += 3) {
        PHASE(it,     0,    5120, x0U0, x0U1, x0V0, x0V1, x2U0, x2U1, x2V0, x2V1);
        PHASE(it + 1, 2560, 0,    x1U0, x1U1, x1V0, x1V1, x0U0, x0U1, x0V0, x0V1);
        PHASE(it + 2, 5120, 2560, x2U0, x2U1, x2V0, x2V1, x1U0, x1U1, x1V0, x1V1);
    }
    // tail: it = 63 (63 % 3 == 0 -> buf0 / X0), no further issues
    asm volatile("s_waitcnt vmcnt(9)" ::: "memory");
    __builtin_amdgcn_s_barrier();
    KSTEP(0, 0, x0U0, x0U1);
    KSTEP(0, 1, x0V0, x0V1);

    // drain wrapped/duplicate issues before s_log aliases the stage memory
    asm volatile("s_waitcnt vmcnt(0)" ::: "memory");
    __syncthreads();

    // ---- write logits; C layout col=lane&15, row=(lane>>4)*4+reg ----
    const int crow  = mh * 16 + (lane >> 4) * 4;
    const int ccol0 = nh * 80 + (lane & 15);
#pragma unroll
    for (int t = 0; t < 5; ++t)
#pragma unroll
        for (int r = 0; r < 4; ++r)
            s_log[(crow + r) * 161 + ccol0 + t * 16] =
                (accH[t][r] + accL[t][r] * (1.0f / 2048.f)) * (1.0f / 64.f);
    __syncthreads();

    // ---- per-token softmax + group top-3 + expert top-6 (threads 0..63) ----
    if (tid < BM) {
        const float* L = &s_log[tid * 161];
        float gmax[8];
        float mx = -3.4e38f;
#pragma unroll
        for (int g = 0; g < 8; ++g) {
            float m = L[g * 20];
            for (int j = 1; j < 20; ++j) m = fmaxf(m, L[g * 20 + j]);
            gmax[g] = m;
            mx = fmaxf(mx, m);
        }
        float sum = 0.f;
        for (int e = 0; e < NE; ++e) sum += __expf(L[e] - mx);
        float inv = 1.0f / sum;
        s_mx[tid]  = mx;
        s_inv[tid] = inv;

        // top-3 groups, lax.top_k tie semantics (value desc, index asc)
        unsigned sel = 0;
        float pv = 3.4e38f; int pi = -1;
        for (int it = 0; it < 3; ++it) {
            float bv = -3.4e38f; int bi = 0;
            for (int g = 0; g < 8; ++g) {
                float v = gmax[g];
                bool below = (v < pv) || (v == pv && g > pi);
                if (below && v > bv) { bv = v; bi = g; }
            }
            sel |= 1u << bi;
            pv = bv; pi = bi;
        }

        // top-6 experts within selected groups
        const int tok = row0 + tid;
        float pv2 = 3.4e38f; int pi2 = -1;
        for (int it = 0; it < 6; ++it) {
            float bv = -3.4e38f; int bi = 0;
            for (int g = 0; g < 8; ++g) {
                if (!((sel >> g) & 1u)) continue;
                for (int j = 0; j < 20; ++j) {
                    int e = g * 20 + j;
                    float v = L[e];
                    bool below = (v < pv2) || (v == pv2 && e > pi2);
                    if (below && v > bv) { bv = v; bi = e; }
                }
            }
            pv2 = bv; pi2 = bi;
            outIdx[(size_t)tok * 6 + it] = (float)bi;
            outW[(size_t)tok * 6 + it]   = __expf(bv - mx) * inv * 16.0f;
            atomicAdd(&s_cnt[bi], 1);
        }
    }
    __syncthreads();

    // ---- per-block expert score-sum + counts -> global (batch, expert) bins ----
    if (tid < NE) {
        float ss = 0.f;
        for (int t2 = 0; t2 < BM; ++t2)
            ss += __expf(s_log[t2 * 161 + tid] - s_mx[t2]) * s_inv[t2];
        const int b = row0 >> 12;   // 4096 tokens per batch
        atomicAdd(&gssum[b * NE + tid], ss);
        atomicAdd(&gcnt[b * NE + tid], (float)s_cnt[tid]);
    }
}

__global__ __launch_bounds__(64) void aux_kernel(
    const float* __restrict__ gcnt, const float* __restrict__ gssum,
    float* __restrict__ out)
{
    const int lane = threadIdx.x;
    float part = 0.f;
    if (lane < 32) {
        const int b = lane >> 3, g = lane & 7;
        const float* cn = gcnt  + b * NE + g * 20;
        const float* sm = gssum + b * NE + g * 20;
        float s1 = 0.f, sc = 0.f, sms = 0.f;
        for (int j = 0; j < 20; ++j) {
            float ce = cn[j] * (1.0f / 153.6f);   // counts / (s*k/E)
            float ms = sm[j] * (1.0f / 4096.0f);  // mean over s
            s1  += ce * ms;
            sc  += cn[j];
            sms += ms;
        }
        float ceg = sc * (1.0f / 153.6f) * (1.0f / 20.0f);
        float msg = sms * (1.0f / 20.0f);
        float ce2 = sc * (1.0f / 1536.0f);        // counts_g / (M*s/G)
        part = s1 + ceg * msg + ce2 * msg;
    }
#pragma unroll
    for (int off = 32; off > 0; off >>= 1) part += __shfl_down(part, off);
    if (lane == 0) out[0] = part * (0.001f * 0.25f);  // ALPHA * mean over B=4
}

extern "C" void kernel_launch(void* const* d_in, const int* in_sizes, int n_in,
                              void* d_out, int out_size, void* d_ws, size_t ws_size,
                              hipStream_t stream)
{
    (void)in_sizes; (void)n_in; (void)out_size; (void)ws_size;
    const float* x = (const float*)d_in[0];
    const float* w = (const float*)d_in[1];
    float* out = (float*)d_out;

    _Float16* Wf  = (_Float16*)d_ws;                  // [128][2][10][64][8] halves
    float* gcnt  = (float*)(Wf + (size_t)NE * H * 2); // [4][160]
    float* gssum = gcnt + 4 * NE;                     // [4][160]

    hipMemsetAsync(gcnt, 0, 2 * 4 * NE * sizeof(float), stream);

    prep_kernel<<<(NE * H / 8) / 256, 256, 0, stream>>>(w, Wf);
    gate_kernel<<<16384 / BM, TPB, 0, stream>>>(
        x, Wf, out, out + 98304, gcnt, gssum);
    aux_kernel<<<1, 64, 0, stream>>>(gcnt, gssum, out + 196608);
}